// Round 2
// baseline (97.091 us; speedup 1.0000x reference)
//
#include <hip/hip_runtime.h>
#include <cstdint>

// HMQSoftmax: exp2(floor(x/ln2)) -> row sum -> quake rsqrt (bf16 magic + 1 Newton)
// -> v = exp*rs*rs -> block-FP quant (block=16, 8-bit signed mantissa, shared exp).
// Rows of 2048 f32. Bit-exact replication of the numpy/JAX f32 op sequence.
//
// R2: IEEE f32 divide replaced by double-precision reciprocal multiply.
// Correctness: need floor(RN_f32(x / ln2f)). ln2f = 1453635 * 2^-21 (21-bit odd
// mantissa), so any exact quotient x/ln2f is >= 2^-45.5 (relative) away from every
// f32 rounding boundary; (double)x * RN_d(1/ln2f) carries <= ~2^-52 relative error,
// hence RN_f32 of the double product == RN_f32 of the f32 division, always.
// ldexpf/frexpf replaced by exponent-field bit ops (all values normal, > 0).

#define LN2F 0.69314718055994530942f
#define COLS 2048

__global__ __launch_bounds__(256) void hmq_softmax_kernel(
    const float* __restrict__ x, float* __restrict__ out) {
    const int tid = threadIdx.x;
    const int rowLocal = tid >> 7;       // 2 rows per block
    const int lane128 = tid & 127;       // 128 threads per row
    const long long row = (long long)blockIdx.x * 2 + rowLocal;
    const float* xr = x + row * COLS;
    float* outr = out + row * COLS;

    // ---- load 16 elements (4 x float4, stride 128 float4s) : fully coalesced ----
    float4 xin[4];
#pragma unroll
    for (int k = 0; k < 4; ++k)
        xin[k] = reinterpret_cast<const float4*>(xr)[lane128 + 128 * k];

    // ---- exp2(floor(x / ln2)) (exact powers of two) + partial sum ----
    const double INV_LN2_D = 1.0 / (double)LN2F;   // RN_d(1/ln2f)
    float e[16];
    float psum = 0.0f;
#pragma unroll
    for (int k = 0; k < 4; ++k) {
        float xs[4] = {xin[k].x, xin[k].y, xin[k].z, xin[k].w};
#pragma unroll
        for (int j = 0; j < 4; ++j) {
            float qr = (float)((double)xs[j] * INV_LN2_D);  // == RN_f32(x / ln2f)
            int qi = (int)floorf(qr);
            float ev = __uint_as_float((uint32_t)(qi + 127) << 23);  // exact 2^qi
            e[k * 4 + j] = ev;
            psum += ev;                  // exact: powers of 2, sum < 2^(qmin+24)
        }
    }

    // ---- row sum: wave shuffle reduce (order-independent: all adds exact) ----
    float wsum = psum;
#pragma unroll
    for (int off = 1; off < 64; off <<= 1)
        wsum += __shfl_xor(wsum, off, 64);

    __shared__ float lds[4];
    const int wave = tid >> 6;
    if ((tid & 63) == 0) lds[wave] = wsum;
    __syncthreads();
    const float s = lds[rowLocal * 2] + lds[rowLocal * 2 + 1];

    // ---- quake rsqrt: bf16 RNE cast, int16 magic, 1 Newton step (bit-exact) ----
    uint32_t ub = __float_as_uint(s);
    uint32_t lsb = (ub >> 16) & 1u;
    uint16_t bbits = (uint16_t)((ub + 0x7FFFu + lsb) >> 16);  // f32->bf16 RNE (s>0, finite)
    int16_t ii = (int16_t)bbits;
    ii = (int16_t)(24375 - (ii >> 1));
    float y = __uint_as_float(((uint32_t)(uint16_t)ii) << 16);
    float xh = __fmul_rn(s, 0.5f);
    float t = __fmul_rn(__fmul_rn(xh, y), y);
    float r = __fsub_rn(1.5f, t);        // separate ops: no FMA contraction
    float rs = __fmul_rn(y, r);

    // ---- v = (e*rs)*rs ; BFP quant per 16-block (4 lanes per block) ----
#pragma unroll
    for (int k = 0; k < 4; ++k) {
        float v[4];
        float m = 0.0f;
#pragma unroll
        for (int j = 0; j < 4; ++j) {
            v[j] = __fmul_rn(__fmul_rn(e[k * 4 + j], rs), rs);  // all > 0
            m = fmaxf(m, v[j]);
        }
        // maxabs across the 4-lane group owning this 16-block
        m = fmaxf(m, __shfl_xor(m, 1, 64));
        m = fmaxf(m, __shfl_xor(m, 2, 64));
        // shared_exp = floor(log2(m)) + 1: m in [2^(ex-1), 2^ex), ex from exponent field.
        // m > 0 always (every v > 0), and always normal -> pure bit extraction.
        int ex = (int)((__float_as_uint(m) >> 23) & 0xFFu) - 126;
        float scale = __uint_as_float((uint32_t)(ex - 7 + 127) << 23);
        float inv_scale = __uint_as_float((uint32_t)(7 - ex + 127) << 23);
        float4 o;
        float* op = &o.x;
#pragma unroll
        for (int j = 0; j < 4; ++j) {
            float qv = rintf(__fmul_rn(v[j], inv_scale));  // exact scale; half-to-even
            qv = fminf(fmaxf(qv, -128.0f), 127.0f);
            op[j] = __fmul_rn(qv, scale);
        }
        reinterpret_cast<float4*>(outr)[lane128 + 128 * k] = o;
    }
}

extern "C" void kernel_launch(void* const* d_in, const int* in_sizes, int n_in,
                              void* d_out, int out_size, void* d_ws, size_t ws_size,
                              hipStream_t stream) {
    const float* x = (const float*)d_in[0];
    float* out = (float*)d_out;
    const long long total = in_sizes[0];
    const int nrows = (int)(total / COLS);        // 32768
    const int grid = nrows / 2;                   // 2 rows per 256-thread block
    hmq_softmax_kernel<<<grid, 256, 0, stream>>>(x, out);
}

// Round 4
// 90.611 us; speedup vs baseline: 1.0715x; 1.0715x over previous
//
#include <hip/hip_runtime.h>
#include <cstdint>

// HMQSoftmax: exp2(floor(x/ln2)) -> row sum -> quake rsqrt (bf16 magic + 1 Newton)
// -> v = exp*rs*rs -> block-FP quant (block=16, 8-bit signed mantissa, shared exp).
// Rows of 2048 f32. Bit-exact replication of the numpy/JAX f32 op sequence.
//
// R4 = R3 with ext_vector_type for the nontemporal builtins (HIP_vector_type
// float4 is a struct and is rejected; clang ext vectors are accepted).
// One row per wave64 (no __syncthreads, no LDS), 8 independent nontemporal
// 16B loads per lane for MLP, in-place transform to cap VGPRs.
// Numerics identical to the passing R2 kernel:
//  - floor(RN_f32(x/ln2f)) via (double)x * RN_d(1/ln2f): ln2f has a 21-bit odd
//    mantissa so exact quotients are >= 2^-45.5 (rel) from any f32 rounding
//    boundary; the double product's <= 2^-52 error can't cross one.
//  - all sums exact (powers of two, sum < 2^(qmin+24)) -> order-independent.
//  - quake rsqrt: bf16 RNE bit-cast, int16 magic 24375, Newton with explicit
//    __fmul_rn/__fsub_rn (no FMA contraction).

#define LN2F 0.69314718055994530942f
#define COLS 2048

typedef float f32x4 __attribute__((ext_vector_type(4)));

__global__ __launch_bounds__(256) void hmq_softmax_kernel(
    const float* __restrict__ x, float* __restrict__ out) {
    const int tid = threadIdx.x;
    const int wave = tid >> 6;                 // 4 rows per block, 1 row per wave
    const int lane = tid & 63;
    const long long row = (long long)blockIdx.x * 4 + wave;
    const f32x4* xr = reinterpret_cast<const f32x4*>(x + row * COLS);
    f32x4* outr = reinterpret_cast<f32x4*>(out + row * COLS);

    // ---- 8 independent nontemporal 16B loads (32 elems/lane, coalesced) ----
    f32x4 d[8];
#pragma unroll
    for (int k = 0; k < 8; ++k)
        d[k] = __builtin_nontemporal_load(&xr[lane + 64 * k]);

    // ---- in-place: d <- exp2(floor(x/ln2)); accumulate exact partial sum ----
    const double INV_LN2_D = 1.0 / (double)LN2F;   // RN_d(1/ln2f)
    float psum = 0.0f;
#pragma unroll
    for (int k = 0; k < 8; ++k) {
#pragma unroll
        for (int j = 0; j < 4; ++j) {
            float qr = (float)((double)d[k][j] * INV_LN2_D);  // == RN_f32(x/ln2f)
            int qi = __float2int_rd(qr);                       // floor-convert
            float ev = __uint_as_float((uint32_t)(qi + 127) << 23);  // exact 2^qi
            d[k][j] = ev;
            psum += ev;
        }
    }

    // ---- row sum: 6-step wave shuffle reduce (exact -> order-independent) ----
    float s = psum;
#pragma unroll
    for (int off = 1; off < 64; off <<= 1)
        s += __shfl_xor(s, off, 64);

    // ---- quake rsqrt: bf16 RNE cast, int16 magic, 1 Newton step (bit-exact) ----
    uint32_t ub = __float_as_uint(s);
    uint32_t lsb = (ub >> 16) & 1u;
    uint16_t bbits = (uint16_t)((ub + 0x7FFFu + lsb) >> 16);  // f32->bf16 RNE
    int16_t ii = (int16_t)bbits;
    ii = (int16_t)(24375 - (ii >> 1));
    float y = __uint_as_float(((uint32_t)(uint16_t)ii) << 16);
    float xh = __fmul_rn(s, 0.5f);
    float t = __fmul_rn(__fmul_rn(xh, y), y);
    float r = __fsub_rn(1.5f, t);        // separate ops: no FMA contraction
    float rs = __fmul_rn(y, r);

    // ---- v = (e*rs)*rs ; BFP quant per 16-block (4 consecutive lanes/block) ----
#pragma unroll
    for (int k = 0; k < 8; ++k) {
        float m = 0.0f;
#pragma unroll
        for (int j = 0; j < 4; ++j) {
            d[k][j] = __fmul_rn(__fmul_rn(d[k][j], rs), rs);  // all > 0
            m = fmaxf(m, d[k][j]);
        }
        // maxabs across the aligned 4-lane group owning this 16-block
        m = fmaxf(m, __shfl_xor(m, 1, 64));
        m = fmaxf(m, __shfl_xor(m, 2, 64));
        // shared_exp = floor(log2(m)) + 1 via exponent field (m > 0, normal)
        int ex = (int)((__float_as_uint(m) >> 23) & 0xFFu) - 126;
        float scale = __uint_as_float((uint32_t)(ex - 7 + 127) << 23);
        float inv_scale = __uint_as_float((uint32_t)(7 - ex + 127) << 23);
        f32x4 o;
#pragma unroll
        for (int j = 0; j < 4; ++j) {
            float qv = rintf(__fmul_rn(d[k][j], inv_scale));  // exact; half-even
            qv = fminf(fmaxf(qv, -128.0f), 127.0f);
            o[j] = __fmul_rn(qv, scale);
        }
        __builtin_nontemporal_store(o, &outr[lane + 64 * k]);
    }
}

extern "C" void kernel_launch(void* const* d_in, const int* in_sizes, int n_in,
                              void* d_out, int out_size, void* d_ws, size_t ws_size,
                              hipStream_t stream) {
    const float* x = (const float*)d_in[0];
    float* out = (float*)d_out;
    const long long total = in_sizes[0];
    const int nrows = (int)(total / COLS);        // 32768
    const int grid = nrows / 4;                   // 4 rows (4 waves) per block
    hmq_softmax_kernel<<<grid, 256, 0, stream>>>(x, out);
}